// Round 4
// baseline (17.870 us; speedup 1.0000x reference)
//
#include <hip/hip_runtime.h>

// out[i] = int32( uint(a[i]) XOR uint(b[i]) )
// a,b are exact non-negative integers < 2^20 stored in float32.
// The reference's bit-extract + SwiGLU-multiply XOR reduces exactly to
// integer XOR. JAX x64 is disabled, so the reference's int64 output is
// actually int32 — the harness reads d_out as int32.
//
// 8 elements/thread: two float4 loads per operand, nontemporal i32x4 stores
// (output is write-only; keep inputs in L2/L3 for replays).

typedef int   i32x4 __attribute__((ext_vector_type(4)));
typedef float f32x4 __attribute__((ext_vector_type(4)));

__global__ void __launch_bounds__(256) xor_i32_kernel8(
    const float* __restrict__ a,
    const float* __restrict__ b,
    int* __restrict__ out,
    int n)
{
    int i = (blockIdx.x * blockDim.x + threadIdx.x) * 8;
    if (i + 7 < n) {
        f32x4 va0 = *reinterpret_cast<const f32x4*>(a + i);
        f32x4 va1 = *reinterpret_cast<const f32x4*>(a + i + 4);
        f32x4 vb0 = *reinterpret_cast<const f32x4*>(b + i);
        f32x4 vb1 = *reinterpret_cast<const f32x4*>(b + i + 4);
        i32x4 vo0, vo1;
        vo0.x = ((int)va0.x) ^ ((int)vb0.x);
        vo0.y = ((int)va0.y) ^ ((int)vb0.y);
        vo0.z = ((int)va0.z) ^ ((int)vb0.z);
        vo0.w = ((int)va0.w) ^ ((int)vb0.w);
        vo1.x = ((int)va1.x) ^ ((int)vb1.x);
        vo1.y = ((int)va1.y) ^ ((int)vb1.y);
        vo1.z = ((int)va1.z) ^ ((int)vb1.z);
        vo1.w = ((int)va1.w) ^ ((int)vb1.w);
        __builtin_nontemporal_store(vo0, reinterpret_cast<i32x4*>(out + i));
        __builtin_nontemporal_store(vo1, reinterpret_cast<i32x4*>(out + i + 4));
    } else if (i < n) {
        for (; i < n; ++i) {
            out[i] = ((int)a[i]) ^ ((int)b[i]);
        }
    }
}

extern "C" void kernel_launch(void* const* d_in, const int* in_sizes, int n_in,
                              void* d_out, int out_size, void* d_ws, size_t ws_size,
                              hipStream_t stream)
{
    const float* a = (const float*)d_in[0];
    const float* b = (const float*)d_in[1];
    int* out = (int*)d_out;
    int n = in_sizes[0];

    int elems8 = (n + 7) / 8;              // number of 8-element work items
    int block = 256;
    int grid = (elems8 + block - 1) / block;
    xor_i32_kernel8<<<grid, block, 0, stream>>>(a, b, out, n);
}

// Round 5
// 10.063 us; speedup vs baseline: 1.7758x; 1.7758x over previous
//
#include <hip/hip_runtime.h>

// out[i] = int32( uint(a[i]) XOR uint(b[i]) )
// a,b are exact non-negative integers < 2^20 stored in float32.
// The reference's bit-extract + SwiGLU-multiply XOR reduces exactly to
// integer XOR. JAX x64 is disabled, so the reference's int64 output is
// actually int32 — the harness reads d_out as int32.
//
// 4 elements/thread, float4 loads, regular (L2-cached) int4 stores.
// Round-4 experiment showed nontemporal stores + 8/thread regressed
// 10.1 -> 17.9 us; this is the known-good configuration.
__global__ void __launch_bounds__(256) xor_i32_kernel(
    const float* __restrict__ a,
    const float* __restrict__ b,
    int* __restrict__ out,
    int n)
{
    int i = (blockIdx.x * blockDim.x + threadIdx.x) * 4;
    if (i + 3 < n) {
        float4 va = *reinterpret_cast<const float4*>(a + i);
        float4 vb = *reinterpret_cast<const float4*>(b + i);
        int4 vo;
        vo.x = ((int)va.x) ^ ((int)vb.x);
        vo.y = ((int)va.y) ^ ((int)vb.y);
        vo.z = ((int)va.z) ^ ((int)vb.z);
        vo.w = ((int)va.w) ^ ((int)vb.w);
        *reinterpret_cast<int4*>(out + i) = vo;
    } else if (i < n) {
        for (; i < n; ++i) {
            out[i] = ((int)a[i]) ^ ((int)b[i]);
        }
    }
}

extern "C" void kernel_launch(void* const* d_in, const int* in_sizes, int n_in,
                              void* d_out, int out_size, void* d_ws, size_t ws_size,
                              hipStream_t stream)
{
    const float* a = (const float*)d_in[0];
    const float* b = (const float*)d_in[1];
    int* out = (int*)d_out;
    int n = in_sizes[0];

    int elems4 = (n + 3) / 4;              // number of 4-element work items
    int block = 256;
    int grid = (elems4 + block - 1) / block;
    xor_i32_kernel<<<grid, block, 0, stream>>>(a, b, out, n);
}